// Round 1
// baseline (989.082 us; speedup 1.0000x reference)
//
#include <hip/hip_runtime.h>
#include <math.h>

#define NFEAT 128

// ---------------- CSR build ----------------

__global__ void k_init(float* degf, int* cnt, int N) {
  int i = blockIdx.x * blockDim.x + threadIdx.x;
  if (i < N) { degf[i] = 1.0f; cnt[i] = 0; }  // 1.0f = self-loop weight
}

__global__ void k_edge_deg(const int* __restrict__ src, const int* __restrict__ dst,
                           const float* __restrict__ ew, float* degf, int* cnt, int E) {
  int e = blockIdx.x * blockDim.x + threadIdx.x;
  if (e < E) {
    int d = dst[e];
    atomicAdd(&degf[d], ew[e]);
    atomicAdd(&cnt[d], 1);
  }
}

__global__ void k_dis(const float* __restrict__ degf, float* dis, int N) {
  int i = blockIdx.x * blockDim.x + threadIdx.x;
  if (i < N) {
    float dg = degf[i];
    dis[i] = dg > 0.f ? 1.0f / sqrtf(dg) : 0.0f;
  }
}

// single-block exclusive scan of (cnt[i]+1) -> rowptr
__global__ __launch_bounds__(1024) void k_scan(const int* __restrict__ cnt, int* rowptr,
                                               int N, int M) {
  __shared__ int sums[1024];
  int t = threadIdx.x;
  int C = (N + 1023) >> 10;
  int beg = t * C; if (beg > N) beg = N;
  int end = beg + C; if (end > N) end = N;
  int s = 0;
  for (int i = beg; i < end; i++) s += cnt[i] + 1;
  sums[t] = s;
  __syncthreads();
  for (int off = 1; off < 1024; off <<= 1) {
    int v = (t >= off) ? sums[t - off] : 0;
    __syncthreads();
    sums[t] += v;
    __syncthreads();
  }
  int run = sums[t] - s;  // exclusive offset for this thread's chunk
  for (int i = beg; i < end; i++) { rowptr[i] = run; run += cnt[i] + 1; }
  if (t == 0) rowptr[N] = M;
}

__global__ void k_selfloop(const int* __restrict__ rowptr, const float* __restrict__ dis,
                           int* col, float* wn, int* cursor, int N) {
  int i = blockIdx.x * blockDim.x + threadIdx.x;
  if (i < N) {
    int p = rowptr[i];
    float d = dis[i];
    col[p] = i;
    wn[p] = d * d;      // dis[i] * 1.0 * dis[i]
    cursor[i] = p + 1;
  }
}

__global__ void k_fill(const int* __restrict__ src, const int* __restrict__ dst,
                       const float* __restrict__ ew, const float* __restrict__ dis,
                       int* cursor, int* col, float* wn, int E) {
  int e = blockIdx.x * blockDim.x + threadIdx.x;
  if (e < E) {
    int s = src[e], d = dst[e];
    int p = atomicAdd(&cursor[d], 1);
    col[p] = s;
    wn[p] = dis[s] * ew[e] * dis[d];
  }
}

// ---------------- dense GEMM: Y[N,128] = X[N,128] @ W[128,128] ----------------
// 256 threads = 4 waves; 32-row tile; lane owns features (2l, 2l+1); wave owns 8 rows.
// LDS: x-tile 16KB + half-of-W 32KB = 48KB (two k-phases per tile).

__global__ __launch_bounds__(256) void k_gemm128(const float* __restrict__ X,
                                                 const float* __restrict__ W,
                                                 float* __restrict__ Y,
                                                 int N, int numTiles) {
  __shared__ float sW[64 * 128];
  __shared__ float sX[32 * 128];
  int t = threadIdx.x, wave = t >> 6, lane = t & 63;

  for (int tile = blockIdx.x; tile < numTiles; tile += gridDim.x) {
    int rowBase = tile * 32;
    __syncthreads();  // prior tile's LDS reads done before overwrite
    {
      const float4* X4 = (const float4*)X;
      float4* sX4 = (float4*)sX;
      for (int i = t; i < 1024; i += 256) {
        int gr = rowBase + (i >> 5);
        sX4[i] = (gr < N) ? X4[(size_t)gr * 32 + (i & 31)] : make_float4(0.f, 0.f, 0.f, 0.f);
      }
    }
    float acc[8][2];
#pragma unroll
    for (int r = 0; r < 8; r++) { acc[r][0] = 0.f; acc[r][1] = 0.f; }

    const float* xb = sX + wave * 8 * 128;
    for (int ph = 0; ph < 2; ph++) {
      __syncthreads();  // phase-0 compute done (sW reads) / sX load done
      {
        const float4* W4 = (const float4*)(W + ph * 64 * 128);
        float4* sW4 = (float4*)sW;
        for (int i = t; i < 2048; i += 256) sW4[i] = W4[i];
      }
      __syncthreads();
      int k0 = ph * 64;
#pragma unroll 4
      for (int k = 0; k < 64; k += 4) {
        float4 xv[8];
#pragma unroll
        for (int r = 0; r < 8; r++) xv[r] = *(const float4*)(xb + r * 128 + k0 + k);
#pragma unroll
        for (int kk = 0; kk < 4; kk++) {
          float2 wv = *(const float2*)(sW + (k + kk) * 128 + 2 * lane);
#pragma unroll
          for (int r = 0; r < 8; r++) {
            float xs = (&xv[r].x)[kk];
            acc[r][0] = fmaf(xs, wv.x, acc[r][0]);
            acc[r][1] = fmaf(xs, wv.y, acc[r][1]);
          }
        }
      }
    }
#pragma unroll
    for (int r = 0; r < 8; r++) {
      int row = rowBase + wave * 8 + r;
      if (row < N)
        *(float2*)(Y + (size_t)row * 128 + 2 * lane) = make_float2(acc[r][0], acc[r][1]);
    }
  }
}

// ---------------- sparse aggregate, 128-wide: Out = relu(A_norm @ H + b) ----------------
// one wave per dst node; lane owns features (l, l+64)

__global__ __launch_bounds__(256) void k_agg128(const float* __restrict__ H,
                                                const int* __restrict__ rowptr,
                                                const int* __restrict__ col,
                                                const float* __restrict__ wn,
                                                const float* __restrict__ bias,
                                                float* __restrict__ Out, int N) {
  int wave = threadIdx.x >> 6, lane = threadIdx.x & 63;
  int node = blockIdx.x * 4 + wave;
  if (node >= N) return;
  int beg = rowptr[node], end = rowptr[node + 1];
  float acc0 = 0.f, acc1 = 0.f;
  for (int e = beg; e < end; e++) {
    int c = col[e];
    float wv = wn[e];
    const float* hp = H + (size_t)c * 128 + lane;
    acc0 = fmaf(wv, hp[0], acc0);
    acc1 = fmaf(wv, hp[64], acc1);
  }
  float o0 = acc0 + bias[lane];
  float o1 = acc1 + bias[lane + 64];
  Out[(size_t)node * 128 + lane]      = o0 > 0.f ? o0 : 0.f;
  Out[(size_t)node * 128 + 64 + lane] = o1 > 0.f ? o1 : 0.f;
}

// ---------------- z[n] = dot(H[n,:], W3) ----------------

__global__ __launch_bounds__(256) void k_gemv(const float* __restrict__ H,
                                              const float* __restrict__ W3,
                                              float* __restrict__ z, int N) {
  int wave = threadIdx.x >> 6, lane = threadIdx.x & 63;
  int node = blockIdx.x * 4 + wave;
  if (node >= N) return;
  const float* hp = H + (size_t)node * 128;
  float p = hp[lane] * W3[lane] + hp[lane + 64] * W3[lane + 64];
#pragma unroll
  for (int off = 32; off > 0; off >>= 1) p += __shfl_down(p, off, 64);
  if (lane == 0) z[node] = p;
}

// ---------------- scalar aggregate + bias + relu ----------------

__global__ void k_aggs(const float* __restrict__ z, const int* __restrict__ rowptr,
                       const int* __restrict__ col, const float* __restrict__ wn,
                       const float* __restrict__ b3, float* __restrict__ out, int N) {
  int n = blockIdx.x * blockDim.x + threadIdx.x;
  if (n >= N) return;
  float acc = 0.f;
  int end = rowptr[n + 1];
  for (int e = rowptr[n]; e < end; e++) acc = fmaf(wn[e], z[col[e]], acc);
  acc += b3[0];
  out[n] = acc > 0.f ? acc : 0.f;
}

// ---------------- launch ----------------

extern "C" void kernel_launch(void* const* d_in, const int* in_sizes, int n_in,
                              void* d_out, int out_size, void* d_ws, size_t ws_size,
                              hipStream_t stream) {
  const float* x  = (const float*)d_in[0];
  const int*   ei = (const int*)d_in[1];
  const float* ew = (const float*)d_in[2];
  const float* W1 = (const float*)d_in[3];
  const float* b1 = (const float*)d_in[4];
  const float* W2 = (const float*)d_in[5];
  const float* b2 = (const float*)d_in[6];
  const float* W3 = (const float*)d_in[7];
  const float* b3 = (const float*)d_in[8];
  int N = in_sizes[0] / NFEAT;
  int E = in_sizes[2];
  int M = E + N;
  const int* srcp = ei;
  const int* dstp = ei + E;

  char* p = (char*)d_ws;
  auto carve = [&](size_t bytes) -> void* {
    void* r = (void*)p;
    p += (bytes + 511) & ~(size_t)511;
    return r;
  };
  float* degf   = (float*)carve(sizeof(float) * N);
  int*   cnt    = (int*)  carve(sizeof(int) * N);
  int*   rowptr = (int*)  carve(sizeof(int) * (N + 1));
  int*   cursor = (int*)  carve(sizeof(int) * N);
  float* dis    = (float*)carve(sizeof(float) * N);
  int*   col    = (int*)  carve(sizeof(int) * M);
  float* wn     = (float*)carve(sizeof(float) * M);
  float* t1     = (float*)carve(sizeof(float) * (size_t)N * NFEAT);
  float* t2     = (float*)carve(sizeof(float) * (size_t)N * NFEAT);
  float* z      = (float*)carve(sizeof(float) * N);

  int gN = (N + 255) / 256, gE = (E + 255) / 256;
  k_init<<<gN, 256, 0, stream>>>(degf, cnt, N);
  k_edge_deg<<<gE, 256, 0, stream>>>(srcp, dstp, ew, degf, cnt, E);
  k_dis<<<gN, 256, 0, stream>>>(degf, dis, N);
  k_scan<<<1, 1024, 0, stream>>>(cnt, rowptr, N, M);
  k_selfloop<<<gN, 256, 0, stream>>>(rowptr, dis, col, wn, cursor, N);
  k_fill<<<gE, 256, 0, stream>>>(srcp, dstp, ew, dis, cursor, col, wn, E);

  int numTiles = (N + 31) / 32;
  int gg = numTiles < 768 ? numTiles : 768;
  int gW = (N + 3) / 4;

  k_gemm128<<<gg, 256, 0, stream>>>(x, W1, t1, N, numTiles);
  k_agg128<<<gW, 256, 0, stream>>>(t1, rowptr, col, wn, b1, t2, N);
  k_gemm128<<<gg, 256, 0, stream>>>(t2, W2, t1, N, numTiles);
  k_agg128<<<gW, 256, 0, stream>>>(t1, rowptr, col, wn, b2, t2, N);
  k_gemv<<<gW, 256, 0, stream>>>(t2, W3, z, N);
  k_aggs<<<gN, 256, 0, stream>>>(z, rowptr, col, wn, b3, (float*)d_out, N);
}

// Round 2
// 791.830 us; speedup vs baseline: 1.2491x; 1.2491x over previous
//
#include <hip/hip_runtime.h>
#include <math.h>

#define NFEAT 128

// edge record: .x = col index (int), .y = norm weight (float bits)
typedef int2 EdgeRec;

// ---------------- CSR build ----------------

__global__ void k_init(float* degf, int* cnt, int N) {
  int i = blockIdx.x * blockDim.x + threadIdx.x;
  if (i < N) { degf[i] = 1.0f; cnt[i] = 0; }  // 1.0f = self-loop weight
}

__global__ void k_edge_deg(const int* __restrict__ dst, const float* __restrict__ ew,
                           float* degf, int* cnt, int E) {
  int e = blockIdx.x * blockDim.x + threadIdx.x;
  if (e < E) {
    int d = dst[e];
    atomicAdd(&degf[d], ew[e]);
    atomicAdd(&cnt[d], 1);
  }
}

__global__ void k_dis(const float* __restrict__ degf, float* dis, int N) {
  int i = blockIdx.x * blockDim.x + threadIdx.x;
  if (i < N) {
    float dg = degf[i];
    dis[i] = dg > 0.f ? 1.0f / sqrtf(dg) : 0.0f;
  }
}

// ---- 3-phase parallel exclusive scan of (cnt[i]+1) -> rowptr, 1024 elems/block ----

__global__ __launch_bounds__(256) void k_scan1(const int* __restrict__ cnt, int* bsum, int N) {
  __shared__ int ls[256];
  int b = blockIdx.x, t = threadIdx.x;
  int base = b * 1024 + t * 4;
  int s = 0;
#pragma unroll
  for (int j = 0; j < 4; j++) { int i = base + j; if (i < N) s += cnt[i] + 1; }
  ls[t] = s;
  __syncthreads();
  for (int off = 128; off > 0; off >>= 1) {
    if (t < off) ls[t] += ls[t + off];
    __syncthreads();
  }
  if (t == 0) bsum[b] = ls[0];
}

__global__ __launch_bounds__(1024) void k_scan2(int* bsum, int SB) {
  __shared__ int ls[1024];
  int t = threadIdx.x;
  int v = (t < SB) ? bsum[t] : 0;
  ls[t] = v;
  __syncthreads();
  for (int off = 1; off < 1024; off <<= 1) {
    int u = (t >= off) ? ls[t - off] : 0;
    __syncthreads();
    ls[t] += u;
    __syncthreads();
  }
  if (t < SB) bsum[t] = ls[t] - v;  // exclusive
}

__global__ __launch_bounds__(256) void k_scan3(const int* __restrict__ cnt,
                                               const int* __restrict__ bsum,
                                               int* rowptr, int N, int M) {
  __shared__ int ls[256];
  int b = blockIdx.x, t = threadIdx.x;
  int base = b * 1024 + t * 4;
  int v[4]; int s = 0;
#pragma unroll
  for (int j = 0; j < 4; j++) { int i = base + j; v[j] = (i < N) ? cnt[i] + 1 : 0; s += v[j]; }
  ls[t] = s;
  __syncthreads();
  for (int off = 1; off < 256; off <<= 1) {
    int u = (t >= off) ? ls[t - off] : 0;
    __syncthreads();
    ls[t] += u;
    __syncthreads();
  }
  int run = bsum[b] + ls[t] - s;
#pragma unroll
  for (int j = 0; j < 4; j++) { int i = base + j; if (i < N) { rowptr[i] = run; run += v[j]; } }
  if (b == 0 && t == 0) rowptr[N] = M;
}

__global__ void k_selfloop(const int* __restrict__ rowptr, const float* __restrict__ dis,
                           EdgeRec* ep, int* cursor, int N) {
  int i = blockIdx.x * blockDim.x + threadIdx.x;
  if (i < N) {
    int p = rowptr[i];
    float d = dis[i];
    EdgeRec r; r.x = i; r.y = __float_as_int(d * d);
    ep[p] = r;
    cursor[i] = p + 1;
  }
}

__global__ void k_fill(const int* __restrict__ src, const int* __restrict__ dst,
                       const float* __restrict__ ew, const float* __restrict__ dis,
                       int* cursor, EdgeRec* ep, int E) {
  int e = blockIdx.x * blockDim.x + threadIdx.x;
  if (e < E) {
    int s = src[e], d = dst[e];
    int p = atomicAdd(&cursor[d], 1);
    EdgeRec r; r.x = s; r.y = __float_as_int(dis[s] * ew[e] * dis[d]);
    ep[p] = r;
  }
}

// ---------------- dense GEMM: Y[N,128] = X[N,128] @ W[128,128] ----------------
// Whole W (64 KB) staged in LDS once per persistent block. X read directly from
// global at wave-uniform addresses (broadcast). No barriers in the tile loop.

__global__ __launch_bounds__(256) void k_gemm128(const float* __restrict__ X,
                                                 const float* __restrict__ W,
                                                 float* __restrict__ Y,
                                                 int N, int numTiles) {
  __shared__ float sW[128 * 128];  // 64 KB
  int t = threadIdx.x;
  int wave = __builtin_amdgcn_readfirstlane(t >> 6);
  int lane = t & 63;
  {
    const float4* W4 = (const float4*)W;
    float4* sW4 = (float4*)sW;
    for (int i = t; i < 4096; i += 256) sW4[i] = W4[i];
  }
  __syncthreads();

  for (int tile = blockIdx.x; tile < numTiles; tile += gridDim.x) {
    int rowBase = tile * 32 + wave * 8;
    float acc[8][2];
#pragma unroll
    for (int r = 0; r < 8; r++) { acc[r][0] = 0.f; acc[r][1] = 0.f; }

    const float* xrow[8];
#pragma unroll
    for (int r = 0; r < 8; r++) {
      int row = rowBase + r;
      int rowc = row < N ? row : N - 1;
      xrow[r] = X + (size_t)rowc * 128;
    }

#pragma unroll 2
    for (int k = 0; k < 128; k += 4) {
      float4 xv[8];
#pragma unroll
      for (int r = 0; r < 8; r++) xv[r] = *(const float4*)(xrow[r] + k);
#pragma unroll
      for (int kk = 0; kk < 4; kk++) {
        float2 wv = *(const float2*)(sW + (k + kk) * 128 + 2 * lane);
#pragma unroll
        for (int r = 0; r < 8; r++) {
          float xs = (&xv[r].x)[kk];
          acc[r][0] = fmaf(xs, wv.x, acc[r][0]);
          acc[r][1] = fmaf(xs, wv.y, acc[r][1]);
        }
      }
    }
#pragma unroll
    for (int r = 0; r < 8; r++) {
      int row = rowBase + r;
      if (row < N)
        *(float2*)(Y + (size_t)row * 128 + 2 * lane) = make_float2(acc[r][0], acc[r][1]);
    }
  }
}

// ---------------- sparse aggregate, 128-wide: Out = relu(A_norm @ H + b) ----------------
// one wave per dst node; lane owns features (2l, 2l+1); edges unrolled x4 for MLP

__global__ __launch_bounds__(256) void k_agg128(const float* __restrict__ H,
                                                const int* __restrict__ rowptr,
                                                const EdgeRec* __restrict__ ep,
                                                const float* __restrict__ bias,
                                                float* __restrict__ Out, int N) {
  int wave = __builtin_amdgcn_readfirstlane(threadIdx.x >> 6);
  int lane = threadIdx.x & 63;
  int node = blockIdx.x * 4 + wave;
  if (node >= N) return;
  int beg = rowptr[node], end = rowptr[node + 1];
  float a0 = 0.f, a1 = 0.f;
  int e = beg;
  for (; e + 4 <= end; e += 4) {
    EdgeRec p0 = ep[e], p1 = ep[e + 1], p2 = ep[e + 2], p3 = ep[e + 3];
    float2 h0 = *(const float2*)(H + (size_t)p0.x * 128 + 2 * lane);
    float2 h1 = *(const float2*)(H + (size_t)p1.x * 128 + 2 * lane);
    float2 h2 = *(const float2*)(H + (size_t)p2.x * 128 + 2 * lane);
    float2 h3 = *(const float2*)(H + (size_t)p3.x * 128 + 2 * lane);
    float w0 = __int_as_float(p0.y), w1 = __int_as_float(p1.y);
    float w2 = __int_as_float(p2.y), w3 = __int_as_float(p3.y);
    a0 = fmaf(w0, h0.x, a0); a1 = fmaf(w0, h0.y, a1);
    a0 = fmaf(w1, h1.x, a0); a1 = fmaf(w1, h1.y, a1);
    a0 = fmaf(w2, h2.x, a0); a1 = fmaf(w2, h2.y, a1);
    a0 = fmaf(w3, h3.x, a0); a1 = fmaf(w3, h3.y, a1);
  }
  for (; e < end; e++) {
    EdgeRec p = ep[e];
    float2 h = *(const float2*)(H + (size_t)p.x * 128 + 2 * lane);
    float w = __int_as_float(p.y);
    a0 = fmaf(w, h.x, a0); a1 = fmaf(w, h.y, a1);
  }
  float2 bv = *(const float2*)(bias + 2 * lane);
  float o0 = a0 + bv.x, o1 = a1 + bv.y;
  o0 = o0 > 0.f ? o0 : 0.f;
  o1 = o1 > 0.f ? o1 : 0.f;
  *(float2*)(Out + (size_t)node * 128 + 2 * lane) = make_float2(o0, o1);
}

// ---- layer-2 aggregate fused with W3 dot: z[node] = relu(agg + b2) . W3 ----

__global__ __launch_bounds__(256) void k_agg_final(const float* __restrict__ H,
                                                   const int* __restrict__ rowptr,
                                                   const EdgeRec* __restrict__ ep,
                                                   const float* __restrict__ bias,
                                                   const float* __restrict__ W3,
                                                   float* __restrict__ z, int N) {
  int wave = __builtin_amdgcn_readfirstlane(threadIdx.x >> 6);
  int lane = threadIdx.x & 63;
  int node = blockIdx.x * 4 + wave;
  if (node >= N) return;
  int beg = rowptr[node], end = rowptr[node + 1];
  float a0 = 0.f, a1 = 0.f;
  int e = beg;
  for (; e + 4 <= end; e += 4) {
    EdgeRec p0 = ep[e], p1 = ep[e + 1], p2 = ep[e + 2], p3 = ep[e + 3];
    float2 h0 = *(const float2*)(H + (size_t)p0.x * 128 + 2 * lane);
    float2 h1 = *(const float2*)(H + (size_t)p1.x * 128 + 2 * lane);
    float2 h2 = *(const float2*)(H + (size_t)p2.x * 128 + 2 * lane);
    float2 h3 = *(const float2*)(H + (size_t)p3.x * 128 + 2 * lane);
    float w0 = __int_as_float(p0.y), w1 = __int_as_float(p1.y);
    float w2 = __int_as_float(p2.y), w3 = __int_as_float(p3.y);
    a0 = fmaf(w0, h0.x, a0); a1 = fmaf(w0, h0.y, a1);
    a0 = fmaf(w1, h1.x, a0); a1 = fmaf(w1, h1.y, a1);
    a0 = fmaf(w2, h2.x, a0); a1 = fmaf(w2, h2.y, a1);
    a0 = fmaf(w3, h3.x, a0); a1 = fmaf(w3, h3.y, a1);
  }
  for (; e < end; e++) {
    EdgeRec p = ep[e];
    float2 h = *(const float2*)(H + (size_t)p.x * 128 + 2 * lane);
    float w = __int_as_float(p.y);
    a0 = fmaf(w, h.x, a0); a1 = fmaf(w, h.y, a1);
  }
  float2 bv = *(const float2*)(bias + 2 * lane);
  float o0 = a0 + bv.x, o1 = a1 + bv.y;
  o0 = o0 > 0.f ? o0 : 0.f;
  o1 = o1 > 0.f ? o1 : 0.f;
  float2 w3v = *(const float2*)(W3 + 2 * lane);
  float p = o0 * w3v.x + o1 * w3v.y;
#pragma unroll
  for (int off = 32; off > 0; off >>= 1) p += __shfl_down(p, off, 64);
  if (lane == 0) z[node] = p;
}

// ---------------- scalar aggregate + bias + relu ----------------

__global__ void k_aggs(const float* __restrict__ z, const int* __restrict__ rowptr,
                       const EdgeRec* __restrict__ ep,
                       const float* __restrict__ b3, float* __restrict__ out, int N) {
  int n = blockIdx.x * blockDim.x + threadIdx.x;
  if (n >= N) return;
  float acc = 0.f;
  int end = rowptr[n + 1];
  for (int e = rowptr[n]; e < end; e++) {
    EdgeRec p = ep[e];
    acc = fmaf(__int_as_float(p.y), z[p.x], acc);
  }
  acc += b3[0];
  out[n] = acc > 0.f ? acc : 0.f;
}

// ---------------- launch ----------------

extern "C" void kernel_launch(void* const* d_in, const int* in_sizes, int n_in,
                              void* d_out, int out_size, void* d_ws, size_t ws_size,
                              hipStream_t stream) {
  const float* x  = (const float*)d_in[0];
  const int*   ei = (const int*)d_in[1];
  const float* ew = (const float*)d_in[2];
  const float* W1 = (const float*)d_in[3];
  const float* b1 = (const float*)d_in[4];
  const float* W2 = (const float*)d_in[5];
  const float* b2 = (const float*)d_in[6];
  const float* W3 = (const float*)d_in[7];
  const float* b3 = (const float*)d_in[8];
  int N = in_sizes[0] / NFEAT;
  int E = in_sizes[2];
  int M = E + N;
  const int* srcp = ei;
  const int* dstp = ei + E;

  char* p = (char*)d_ws;
  auto carve = [&](size_t bytes) -> void* {
    void* r = (void*)p;
    p += (bytes + 511) & ~(size_t)511;
    return r;
  };
  float*   degf   = (float*)carve(sizeof(float) * N);
  int*     cnt    = (int*)  carve(sizeof(int) * N);
  int*     rowptr = (int*)  carve(sizeof(int) * (N + 1));
  int*     cursor = (int*)  carve(sizeof(int) * N);
  float*   dis    = (float*)carve(sizeof(float) * N);
  int*     bsum   = (int*)  carve(sizeof(int) * 1024);
  EdgeRec* ep     = (EdgeRec*)carve(sizeof(EdgeRec) * M);
  float*   t1     = (float*)carve(sizeof(float) * (size_t)N * NFEAT);
  float*   t2     = (float*)carve(sizeof(float) * (size_t)N * NFEAT);
  float*   z      = (float*)carve(sizeof(float) * N);

  int gN = (N + 255) / 256, gE = (E + 255) / 256;
  int SB = (N + 1023) / 1024;

  k_init<<<gN, 256, 0, stream>>>(degf, cnt, N);
  k_edge_deg<<<gE, 256, 0, stream>>>(dstp, ew, degf, cnt, E);
  k_dis<<<gN, 256, 0, stream>>>(degf, dis, N);
  k_scan1<<<SB, 256, 0, stream>>>(cnt, bsum, N);
  k_scan2<<<1, 1024, 0, stream>>>(bsum, SB);
  k_scan3<<<SB, 256, 0, stream>>>(cnt, bsum, rowptr, N, M);
  k_selfloop<<<gN, 256, 0, stream>>>(rowptr, dis, ep, cursor, N);
  k_fill<<<gE, 256, 0, stream>>>(srcp, dstp, ew, dis, cursor, ep, E);

  int numTiles = (N + 31) / 32;
  int gg = 512;
  int gW = (N + 3) / 4;

  k_gemm128<<<gg, 256, 0, stream>>>(x, W1, t1, N, numTiles);
  k_agg128<<<gW, 256, 0, stream>>>(t1, rowptr, ep, b1, t2, N);
  k_gemm128<<<gg, 256, 0, stream>>>(t2, W2, t1, N, numTiles);
  k_agg_final<<<gW, 256, 0, stream>>>(t1, rowptr, ep, b2, W3, z, N);
  k_aggs<<<gN, 256, 0, stream>>>(z, rowptr, ep, b3, (float*)d_out, N);
}

// Round 3
// 734.678 us; speedup vs baseline: 1.3463x; 1.0778x over previous
//
#include <hip/hip_runtime.h>
#include <math.h>

#define NFEAT 128

// edge record: .x = col index (int), .y = dis[src]*w (float bits); dis[dst] folded into epilogue
typedef int2 EdgeRec;

// ---------------- CSR build ----------------

__global__ void k_init(unsigned long long* packed, int N) {
  int i = blockIdx.x * blockDim.x + threadIdx.x;
  if (i < N) packed[i] = 0ull;
}

// ONE u64 atomic per edge: count in bits[40..], fixed-point (2^-32) weight sum in bits[0..40).
// Returned old count = this edge's slot offset within its row.
__global__ void k_count64(const int* __restrict__ dst, const float* __restrict__ ew,
                          unsigned long long* packed, int* off, int E) {
  int e = blockIdx.x * blockDim.x + threadIdx.x;
  if (e < E) {
    unsigned long long add = (1ull << 40) | (unsigned long long)(ew[e] * 4294967296.0f);
    unsigned long long old = atomicAdd(&packed[dst[e]], add);
    off[e] = (int)(old >> 40);
  }
}

__global__ void k_dis(const unsigned long long* __restrict__ packed, float* dis, int N) {
  int i = blockIdx.x * blockDim.x + threadIdx.x;
  if (i < N) {
    double s = (double)(packed[i] & ((1ull << 40) - 1)) * 2.3283064365386963e-10;  // /2^32
    float dg = 1.0f + (float)s;  // + self-loop weight
    dis[i] = 1.0f / sqrtf(dg);
  }
}

// ---- 3-phase parallel exclusive scan of (cnt[i]+1) -> rowptr, 1024 elems/block ----

__global__ __launch_bounds__(256) void k_scan1(const unsigned long long* __restrict__ packed,
                                               int* bsum, int N) {
  __shared__ int ls[256];
  int b = blockIdx.x, t = threadIdx.x;
  int base = b * 1024 + t * 4;
  int s = 0;
#pragma unroll
  for (int j = 0; j < 4; j++) { int i = base + j; if (i < N) s += (int)(packed[i] >> 40) + 1; }
  ls[t] = s;
  __syncthreads();
  for (int off = 128; off > 0; off >>= 1) {
    if (t < off) ls[t] += ls[t + off];
    __syncthreads();
  }
  if (t == 0) bsum[b] = ls[0];
}

__global__ __launch_bounds__(1024) void k_scan2(int* bsum, int SB) {
  __shared__ int ls[1024];
  int t = threadIdx.x;
  int v = (t < SB) ? bsum[t] : 0;
  ls[t] = v;
  __syncthreads();
  for (int off = 1; off < 1024; off <<= 1) {
    int u = (t >= off) ? ls[t - off] : 0;
    __syncthreads();
    ls[t] += u;
    __syncthreads();
  }
  if (t < SB) bsum[t] = ls[t] - v;  // exclusive
}

__global__ __launch_bounds__(256) void k_scan3(const unsigned long long* __restrict__ packed,
                                               const int* __restrict__ bsum,
                                               int* rowptr, int N, int M) {
  __shared__ int ls[256];
  int b = blockIdx.x, t = threadIdx.x;
  int base = b * 1024 + t * 4;
  int v[4]; int s = 0;
#pragma unroll
  for (int j = 0; j < 4; j++) {
    int i = base + j;
    v[j] = (i < N) ? (int)(packed[i] >> 40) + 1 : 0;
    s += v[j];
  }
  ls[t] = s;
  __syncthreads();
  for (int off = 1; off < 256; off <<= 1) {
    int u = (t >= off) ? ls[t - off] : 0;
    __syncthreads();
    ls[t] += u;
    __syncthreads();
  }
  int run = bsum[b] + ls[t] - s;
#pragma unroll
  for (int j = 0; j < 4; j++) { int i = base + j; if (i < N) { rowptr[i] = run; run += v[j]; } }
  if (b == 0 && t == 0) rowptr[N] = M;
}

__global__ void k_selfloop(const int* __restrict__ rowptr, const float* __restrict__ dis,
                           EdgeRec* ep, int N) {
  int i = blockIdx.x * blockDim.x + threadIdx.x;
  if (i < N) {
    EdgeRec r; r.x = i; r.y = __float_as_int(dis[i]);  // dis[i]*1.0; *dis[i] applied in epilogue
    ep[rowptr[i]] = r;
  }
}

// no atomics: slot = rowptr[dst] + 1 + off[e]
__global__ void k_fill(const int* __restrict__ src, const int* __restrict__ dst,
                       const float* __restrict__ ew, const float* __restrict__ dis,
                       const int* __restrict__ rowptr, const int* __restrict__ off,
                       EdgeRec* ep, int E) {
  int e = blockIdx.x * blockDim.x + threadIdx.x;
  if (e < E) {
    int s = src[e], d = dst[e];
    int p = rowptr[d] + 1 + off[e];
    EdgeRec r; r.x = s; r.y = __float_as_int(dis[s] * ew[e]);
    ep[p] = r;
  }
}

// ---------------- dense GEMM: Y[N,128] = X[N,128] @ W[128,128] ----------------
// W fully in LDS (64 KB). 16 rows/wave via wave-uniform broadcast loads (16 in flight),
// lane owns output cols (2l, 2l+1). No barriers in the tile loop.

__global__ __launch_bounds__(256) void k_gemm128(const float* __restrict__ X,
                                                 const float* __restrict__ W,
                                                 float* __restrict__ Y,
                                                 int N, int numTiles) {
  __shared__ float sW[128 * 128];  // 64 KB -> 2 blocks/CU
  int t = threadIdx.x;
  int wave = __builtin_amdgcn_readfirstlane(t >> 6);
  int lane = t & 63;
  {
    const float4* W4 = (const float4*)W;
    float4* sW4 = (float4*)sW;
    for (int i = t; i < 4096; i += 256) sW4[i] = W4[i];
  }
  __syncthreads();

  for (int tile = blockIdx.x; tile < numTiles; tile += gridDim.x) {
    int rowBase = tile * 64 + wave * 16;
    float2 acc[16];
#pragma unroll
    for (int r = 0; r < 16; r++) acc[r] = make_float2(0.f, 0.f);

    const float* xbase[16];
#pragma unroll
    for (int r = 0; r < 16; r++) {
      int row = rowBase + r;
      if (row >= N) row = 0;
      xbase[r] = X + (size_t)row * 128;
    }

#pragma unroll 2
    for (int k = 0; k < 128; k += 4) {
      float4 xv[16];
#pragma unroll
      for (int r = 0; r < 16; r++) xv[r] = *(const float4*)(xbase[r] + k);
#pragma unroll
      for (int kk = 0; kk < 4; kk++) {
        float2 wv = *(const float2*)(sW + (k + kk) * 128 + 2 * lane);
#pragma unroll
        for (int r = 0; r < 16; r++) {
          float xs = (&xv[r].x)[kk];
          acc[r].x = fmaf(xs, wv.x, acc[r].x);
          acc[r].y = fmaf(xs, wv.y, acc[r].y);
        }
      }
    }
#pragma unroll
    for (int r = 0; r < 16; r++) {
      int row = rowBase + r;
      if (row < N)
        *(float2*)(Y + (size_t)row * 128 + 2 * lane) = acc[r];
    }
  }
}

// ---------------- sparse aggregate, 128-wide: Out = relu(dis[n]*agg + b) ----------------

__global__ __launch_bounds__(256) void k_agg128(const float* __restrict__ H,
                                                const int* __restrict__ rowptr,
                                                const EdgeRec* __restrict__ ep,
                                                const float* __restrict__ dis,
                                                const float* __restrict__ bias,
                                                float* __restrict__ Out, int N) {
  int wave = __builtin_amdgcn_readfirstlane(threadIdx.x >> 6);
  int lane = threadIdx.x & 63;
  int node = blockIdx.x * 4 + wave;
  if (node >= N) return;
  int beg = rowptr[node], end = rowptr[node + 1];
  float a0 = 0.f, a1 = 0.f;
  int e = beg;
  for (; e + 4 <= end; e += 4) {
    EdgeRec p0 = ep[e], p1 = ep[e + 1], p2 = ep[e + 2], p3 = ep[e + 3];
    float2 h0 = *(const float2*)(H + (size_t)p0.x * 128 + 2 * lane);
    float2 h1 = *(const float2*)(H + (size_t)p1.x * 128 + 2 * lane);
    float2 h2 = *(const float2*)(H + (size_t)p2.x * 128 + 2 * lane);
    float2 h3 = *(const float2*)(H + (size_t)p3.x * 128 + 2 * lane);
    float w0 = __int_as_float(p0.y), w1 = __int_as_float(p1.y);
    float w2 = __int_as_float(p2.y), w3 = __int_as_float(p3.y);
    a0 = fmaf(w0, h0.x, a0); a1 = fmaf(w0, h0.y, a1);
    a0 = fmaf(w1, h1.x, a0); a1 = fmaf(w1, h1.y, a1);
    a0 = fmaf(w2, h2.x, a0); a1 = fmaf(w2, h2.y, a1);
    a0 = fmaf(w3, h3.x, a0); a1 = fmaf(w3, h3.y, a1);
  }
  for (; e < end; e++) {
    EdgeRec p = ep[e];
    float2 h = *(const float2*)(H + (size_t)p.x * 128 + 2 * lane);
    float w = __int_as_float(p.y);
    a0 = fmaf(w, h.x, a0); a1 = fmaf(w, h.y, a1);
  }
  float ds = dis[node];
  float2 bv = *(const float2*)(bias + 2 * lane);
  float o0 = fmaf(ds, a0, bv.x), o1 = fmaf(ds, a1, bv.y);
  o0 = o0 > 0.f ? o0 : 0.f;
  o1 = o1 > 0.f ? o1 : 0.f;
  *(float2*)(Out + (size_t)node * 128 + 2 * lane) = make_float2(o0, o1);
}

// ---- layer-2 aggregate fused with W3 dot: z[node] = relu(dis*agg + b2) . W3 ----

__global__ __launch_bounds__(256) void k_agg_final(const float* __restrict__ H,
                                                   const int* __restrict__ rowptr,
                                                   const EdgeRec* __restrict__ ep,
                                                   const float* __restrict__ dis,
                                                   const float* __restrict__ bias,
                                                   const float* __restrict__ W3,
                                                   float* __restrict__ z, int N) {
  int wave = __builtin_amdgcn_readfirstlane(threadIdx.x >> 6);
  int lane = threadIdx.x & 63;
  int node = blockIdx.x * 4 + wave;
  if (node >= N) return;
  int beg = rowptr[node], end = rowptr[node + 1];
  float a0 = 0.f, a1 = 0.f;
  int e = beg;
  for (; e + 4 <= end; e += 4) {
    EdgeRec p0 = ep[e], p1 = ep[e + 1], p2 = ep[e + 2], p3 = ep[e + 3];
    float2 h0 = *(const float2*)(H + (size_t)p0.x * 128 + 2 * lane);
    float2 h1 = *(const float2*)(H + (size_t)p1.x * 128 + 2 * lane);
    float2 h2 = *(const float2*)(H + (size_t)p2.x * 128 + 2 * lane);
    float2 h3 = *(const float2*)(H + (size_t)p3.x * 128 + 2 * lane);
    float w0 = __int_as_float(p0.y), w1 = __int_as_float(p1.y);
    float w2 = __int_as_float(p2.y), w3 = __int_as_float(p3.y);
    a0 = fmaf(w0, h0.x, a0); a1 = fmaf(w0, h0.y, a1);
    a0 = fmaf(w1, h1.x, a0); a1 = fmaf(w1, h1.y, a1);
    a0 = fmaf(w2, h2.x, a0); a1 = fmaf(w2, h2.y, a1);
    a0 = fmaf(w3, h3.x, a0); a1 = fmaf(w3, h3.y, a1);
  }
  for (; e < end; e++) {
    EdgeRec p = ep[e];
    float2 h = *(const float2*)(H + (size_t)p.x * 128 + 2 * lane);
    float w = __int_as_float(p.y);
    a0 = fmaf(w, h.x, a0); a1 = fmaf(w, h.y, a1);
  }
  float ds = dis[node];
  float2 bv = *(const float2*)(bias + 2 * lane);
  float o0 = fmaf(ds, a0, bv.x), o1 = fmaf(ds, a1, bv.y);
  o0 = o0 > 0.f ? o0 : 0.f;
  o1 = o1 > 0.f ? o1 : 0.f;
  float2 w3v = *(const float2*)(W3 + 2 * lane);
  float p = o0 * w3v.x + o1 * w3v.y;
#pragma unroll
  for (int off = 32; off > 0; off >>= 1) p += __shfl_down(p, off, 64);
  if (lane == 0) z[node] = p;
}

// ---------------- scalar aggregate + bias + relu ----------------

__global__ void k_aggs(const float* __restrict__ z, const int* __restrict__ rowptr,
                       const EdgeRec* __restrict__ ep, const float* __restrict__ dis,
                       const float* __restrict__ b3, float* __restrict__ out, int N) {
  int n = blockIdx.x * blockDim.x + threadIdx.x;
  if (n >= N) return;
  float acc = 0.f;
  int end = rowptr[n + 1];
  for (int e = rowptr[n]; e < end; e++) {
    EdgeRec p = ep[e];
    acc = fmaf(__int_as_float(p.y), z[p.x], acc);
  }
  acc = fmaf(dis[n], acc, b3[0]);
  out[n] = acc > 0.f ? acc : 0.f;
}

// ---------------- launch ----------------

extern "C" void kernel_launch(void* const* d_in, const int* in_sizes, int n_in,
                              void* d_out, int out_size, void* d_ws, size_t ws_size,
                              hipStream_t stream) {
  const float* x  = (const float*)d_in[0];
  const int*   ei = (const int*)d_in[1];
  const float* ew = (const float*)d_in[2];
  const float* W1 = (const float*)d_in[3];
  const float* b1 = (const float*)d_in[4];
  const float* W2 = (const float*)d_in[5];
  const float* b2 = (const float*)d_in[6];
  const float* W3 = (const float*)d_in[7];
  const float* b3 = (const float*)d_in[8];
  int N = in_sizes[0] / NFEAT;
  int E = in_sizes[2];
  int M = E + N;
  const int* srcp = ei;
  const int* dstp = ei + E;

  char* p = (char*)d_ws;
  auto carve = [&](size_t bytes) -> void* {
    void* r = (void*)p;
    p += (bytes + 511) & ~(size_t)511;
    return r;
  };
  unsigned long long* packed = (unsigned long long*)carve(sizeof(unsigned long long) * N);
  int*     off    = (int*)  carve(sizeof(int) * E);
  int*     rowptr = (int*)  carve(sizeof(int) * (N + 1));
  float*   dis    = (float*)carve(sizeof(float) * N);
  int*     bsum   = (int*)  carve(sizeof(int) * 1024);
  EdgeRec* ep     = (EdgeRec*)carve(sizeof(EdgeRec) * M);
  float*   t1     = (float*)carve(sizeof(float) * (size_t)N * NFEAT);
  float*   t2     = (float*)carve(sizeof(float) * (size_t)N * NFEAT);
  float*   z      = (float*)carve(sizeof(float) * N);

  int gN = (N + 255) / 256, gE = (E + 255) / 256;
  int SB = (N + 1023) / 1024;

  k_init<<<gN, 256, 0, stream>>>(packed, N);
  k_count64<<<gE, 256, 0, stream>>>(dstp, ew, packed, off, E);
  k_dis<<<gN, 256, 0, stream>>>(packed, dis, N);
  k_scan1<<<SB, 256, 0, stream>>>(packed, bsum, N);
  k_scan2<<<1, 1024, 0, stream>>>(bsum, SB);
  k_scan3<<<SB, 256, 0, stream>>>(packed, bsum, rowptr, N, M);
  k_selfloop<<<gN, 256, 0, stream>>>(rowptr, dis, ep, N);
  k_fill<<<gE, 256, 0, stream>>>(srcp, dstp, ew, dis, rowptr, off, ep, E);

  int numTiles = (N + 63) / 64;
  int gg = numTiles < 512 ? numTiles : 512;
  int gW = (N + 3) / 4;

  k_gemm128<<<gg, 256, 0, stream>>>(x, W1, t1, N, numTiles);
  k_agg128<<<gW, 256, 0, stream>>>(t1, rowptr, ep, dis, b1, t2, N);
  k_gemm128<<<gg, 256, 0, stream>>>(t2, W2, t1, N, numTiles);
  k_agg_final<<<gW, 256, 0, stream>>>(t1, rowptr, ep, dis, b2, W3, z, N);
  k_aggs<<<gN, 256, 0, stream>>>(z, rowptr, ep, dis, b3, (float*)d_out, N);
}

// Round 4
// 660.279 us; speedup vs baseline: 1.4980x; 1.1127x over previous
//
#include <hip/hip_runtime.h>
#include <math.h>

#define NFEAT 128

// edge record: .x = col index (int), .y = dis[src]*w (float bits); dis[dst] folded into epilogue
typedef int2 EdgeRec;

// ---------------- CSR build ----------------

__global__ void k_init(unsigned long long* packed, int N) {
  int i = blockIdx.x * blockDim.x + threadIdx.x;
  if (i < N) packed[i] = 0ull;
}

// ONE u64 atomic per edge: count in bits[40..], fixed-point (2^-32) weight sum in bits[0..40).
// Returned old count = this edge's slot offset within its row.
__global__ void k_count64(const int* __restrict__ dst, const float* __restrict__ ew,
                          unsigned long long* packed, int* off, int E) {
  int e = blockIdx.x * blockDim.x + threadIdx.x;
  if (e < E) {
    unsigned long long add = (1ull << 40) | (unsigned long long)(ew[e] * 4294967296.0f);
    unsigned long long old = atomicAdd(&packed[dst[e]], add);
    off[e] = (int)(old >> 40);
  }
}

__global__ void k_dis(const unsigned long long* __restrict__ packed, float* dis, int N) {
  int i = blockIdx.x * blockDim.x + threadIdx.x;
  if (i < N) {
    double s = (double)(packed[i] & ((1ull << 40) - 1)) * 2.3283064365386963e-10;  // /2^32
    float dg = 1.0f + (float)s;  // + self-loop weight
    dis[i] = 1.0f / sqrtf(dg);
  }
}

// ---- 3-phase parallel exclusive scan of (cnt[i]+1) -> rowptr, 1024 elems/block ----

__global__ __launch_bounds__(256) void k_scan1(const unsigned long long* __restrict__ packed,
                                               int* bsum, int N) {
  __shared__ int ls[256];
  int b = blockIdx.x, t = threadIdx.x;
  int base = b * 1024 + t * 4;
  int s = 0;
#pragma unroll
  for (int j = 0; j < 4; j++) { int i = base + j; if (i < N) s += (int)(packed[i] >> 40) + 1; }
  ls[t] = s;
  __syncthreads();
  for (int off = 128; off > 0; off >>= 1) {
    if (t < off) ls[t] += ls[t + off];
    __syncthreads();
  }
  if (t == 0) bsum[b] = ls[0];
}

__global__ __launch_bounds__(1024) void k_scan2(int* bsum, int SB) {
  __shared__ int ls[1024];
  int t = threadIdx.x;
  int v = (t < SB) ? bsum[t] : 0;
  ls[t] = v;
  __syncthreads();
  for (int off = 1; off < 1024; off <<= 1) {
    int u = (t >= off) ? ls[t - off] : 0;
    __syncthreads();
    ls[t] += u;
    __syncthreads();
  }
  if (t < SB) bsum[t] = ls[t] - v;  // exclusive
}

__global__ __launch_bounds__(256) void k_scan3(const unsigned long long* __restrict__ packed,
                                               const int* __restrict__ bsum,
                                               int* rowptr, int N, int M) {
  __shared__ int ls[256];
  int b = blockIdx.x, t = threadIdx.x;
  int base = b * 1024 + t * 4;
  int v[4]; int s = 0;
#pragma unroll
  for (int j = 0; j < 4; j++) {
    int i = base + j;
    v[j] = (i < N) ? (int)(packed[i] >> 40) + 1 : 0;
    s += v[j];
  }
  ls[t] = s;
  __syncthreads();
  for (int off = 1; off < 256; off <<= 1) {
    int u = (t >= off) ? ls[t - off] : 0;
    __syncthreads();
    ls[t] += u;
    __syncthreads();
  }
  int run = bsum[b] + ls[t] - s;
#pragma unroll
  for (int j = 0; j < 4; j++) { int i = base + j; if (i < N) { rowptr[i] = run; run += v[j]; } }
  if (b == 0 && t == 0) rowptr[N] = M;
}

__global__ void k_selfloop(const int* __restrict__ rowptr, const float* __restrict__ dis,
                           EdgeRec* ep, int N) {
  int i = blockIdx.x * blockDim.x + threadIdx.x;
  if (i < N) {
    EdgeRec r; r.x = i; r.y = __float_as_int(dis[i]);  // dis[i]*1.0; *dis[i] applied in epilogue
    ep[rowptr[i]] = r;
  }
}

// no atomics: slot = rowptr[dst] + 1 + off[e]
__global__ void k_fill(const int* __restrict__ src, const int* __restrict__ dst,
                       const float* __restrict__ ew, const float* __restrict__ dis,
                       const int* __restrict__ rowptr, const int* __restrict__ off,
                       EdgeRec* ep, int E) {
  int e = blockIdx.x * blockDim.x + threadIdx.x;
  if (e < E) {
    int s = src[e], d = dst[e];
    int p = rowptr[d] + 1 + off[e];
    EdgeRec r; r.x = s; r.y = __float_as_int(dis[s] * ew[e]);
    ep[p] = r;
  }
}

// ---------------- dense GEMM: Y[N,128] = X[N,128] @ W[128,128] ----------------
// 512-thread blocks (8 waves), W fully resident in 64 KB LDS -> 2 blocks/CU = 4 waves/SIMD.
// 8 rows/wave via wave-uniform broadcast loads, explicit register double-buffer so
// next k-step's loads overlap current step's FMAs. No barriers in the tile loop.

__global__ __launch_bounds__(512) void k_gemm128(const float* __restrict__ X,
                                                 const float* __restrict__ W,
                                                 float* __restrict__ Y,
                                                 int N, int numTiles) {
  __shared__ float sW[128 * 128];  // 64 KB -> 2 blocks/CU
  int t = threadIdx.x;
  int wave = __builtin_amdgcn_readfirstlane(t >> 6);  // 0..7
  int lane = t & 63;
  {
    const float4* W4 = (const float4*)W;
    float4* sW4 = (float4*)sW;
    for (int i = t; i < 4096; i += 512) sW4[i] = W4[i];
  }
  __syncthreads();

  for (int tile = blockIdx.x; tile < numTiles; tile += gridDim.x) {
    int rowBase = tile * 64 + wave * 8;
    const float* xb[8];
#pragma unroll
    for (int r = 0; r < 8; r++) {
      int row = rowBase + r;
      if (row >= N) row = 0;
      xb[r] = X + (size_t)row * 128;
    }
    float2 acc[8];
#pragma unroll
    for (int r = 0; r < 8; r++) acc[r] = make_float2(0.f, 0.f);

    float4 cur[8], nxt[8];
#pragma unroll
    for (int r = 0; r < 8; r++) cur[r] = *(const float4*)(xb[r]);

    for (int k = 0; k < 128; k += 4) {
      if (k + 4 < 128) {
#pragma unroll
        for (int r = 0; r < 8; r++) nxt[r] = *(const float4*)(xb[r] + k + 4);
      }
#pragma unroll
      for (int kk = 0; kk < 4; kk++) {
        float2 wv = *(const float2*)(sW + (k + kk) * 128 + 2 * lane);
#pragma unroll
        for (int r = 0; r < 8; r++) {
          float xs = (&cur[r].x)[kk];
          acc[r].x = fmaf(xs, wv.x, acc[r].x);
          acc[r].y = fmaf(xs, wv.y, acc[r].y);
        }
      }
#pragma unroll
      for (int r = 0; r < 8; r++) cur[r] = nxt[r];
    }
#pragma unroll
    for (int r = 0; r < 8; r++) {
      int row = rowBase + r;
      if (row < N)
        *(float2*)(Y + (size_t)row * 128 + 2 * lane) = acc[r];
    }
  }
}

// ---------------- sparse aggregate, 128-wide: Out = relu(dis[n]*agg + b) ----------------

__global__ __launch_bounds__(256) void k_agg128(const float* __restrict__ H,
                                                const int* __restrict__ rowptr,
                                                const EdgeRec* __restrict__ ep,
                                                const float* __restrict__ dis,
                                                const float* __restrict__ bias,
                                                float* __restrict__ Out, int N) {
  int wave = __builtin_amdgcn_readfirstlane(threadIdx.x >> 6);
  int lane = threadIdx.x & 63;
  int node = blockIdx.x * 4 + wave;
  if (node >= N) return;
  int beg = rowptr[node], end = rowptr[node + 1];
  float a0 = 0.f, a1 = 0.f;
  int e = beg;
  for (; e + 4 <= end; e += 4) {
    EdgeRec p0 = ep[e], p1 = ep[e + 1], p2 = ep[e + 2], p3 = ep[e + 3];
    float2 h0 = *(const float2*)(H + (size_t)p0.x * 128 + 2 * lane);
    float2 h1 = *(const float2*)(H + (size_t)p1.x * 128 + 2 * lane);
    float2 h2 = *(const float2*)(H + (size_t)p2.x * 128 + 2 * lane);
    float2 h3 = *(const float2*)(H + (size_t)p3.x * 128 + 2 * lane);
    float w0 = __int_as_float(p0.y), w1 = __int_as_float(p1.y);
    float w2 = __int_as_float(p2.y), w3 = __int_as_float(p3.y);
    a0 = fmaf(w0, h0.x, a0); a1 = fmaf(w0, h0.y, a1);
    a0 = fmaf(w1, h1.x, a0); a1 = fmaf(w1, h1.y, a1);
    a0 = fmaf(w2, h2.x, a0); a1 = fmaf(w2, h2.y, a1);
    a0 = fmaf(w3, h3.x, a0); a1 = fmaf(w3, h3.y, a1);
  }
  for (; e < end; e++) {
    EdgeRec p = ep[e];
    float2 h = *(const float2*)(H + (size_t)p.x * 128 + 2 * lane);
    float w = __int_as_float(p.y);
    a0 = fmaf(w, h.x, a0); a1 = fmaf(w, h.y, a1);
  }
  float ds = dis[node];
  float2 bv = *(const float2*)(bias + 2 * lane);
  float o0 = fmaf(ds, a0, bv.x), o1 = fmaf(ds, a1, bv.y);
  o0 = o0 > 0.f ? o0 : 0.f;
  o1 = o1 > 0.f ? o1 : 0.f;
  *(float2*)(Out + (size_t)node * 128 + 2 * lane) = make_float2(o0, o1);
}

// ---- layer-2 aggregate fused with W3 dot: z[node] = relu(dis*agg + b2) . W3 ----

__global__ __launch_bounds__(256) void k_agg_final(const float* __restrict__ H,
                                                   const int* __restrict__ rowptr,
                                                   const EdgeRec* __restrict__ ep,
                                                   const float* __restrict__ dis,
                                                   const float* __restrict__ bias,
                                                   const float* __restrict__ W3,
                                                   float* __restrict__ z, int N) {
  int wave = __builtin_amdgcn_readfirstlane(threadIdx.x >> 6);
  int lane = threadIdx.x & 63;
  int node = blockIdx.x * 4 + wave;
  if (node >= N) return;
  int beg = rowptr[node], end = rowptr[node + 1];
  float a0 = 0.f, a1 = 0.f;
  int e = beg;
  for (; e + 4 <= end; e += 4) {
    EdgeRec p0 = ep[e], p1 = ep[e + 1], p2 = ep[e + 2], p3 = ep[e + 3];
    float2 h0 = *(const float2*)(H + (size_t)p0.x * 128 + 2 * lane);
    float2 h1 = *(const float2*)(H + (size_t)p1.x * 128 + 2 * lane);
    float2 h2 = *(const float2*)(H + (size_t)p2.x * 128 + 2 * lane);
    float2 h3 = *(const float2*)(H + (size_t)p3.x * 128 + 2 * lane);
    float w0 = __int_as_float(p0.y), w1 = __int_as_float(p1.y);
    float w2 = __int_as_float(p2.y), w3 = __int_as_float(p3.y);
    a0 = fmaf(w0, h0.x, a0); a1 = fmaf(w0, h0.y, a1);
    a0 = fmaf(w1, h1.x, a0); a1 = fmaf(w1, h1.y, a1);
    a0 = fmaf(w2, h2.x, a0); a1 = fmaf(w2, h2.y, a1);
    a0 = fmaf(w3, h3.x, a0); a1 = fmaf(w3, h3.y, a1);
  }
  for (; e < end; e++) {
    EdgeRec p = ep[e];
    float2 h = *(const float2*)(H + (size_t)p.x * 128 + 2 * lane);
    float w = __int_as_float(p.y);
    a0 = fmaf(w, h.x, a0); a1 = fmaf(w, h.y, a1);
  }
  float ds = dis[node];
  float2 bv = *(const float2*)(bias + 2 * lane);
  float o0 = fmaf(ds, a0, bv.x), o1 = fmaf(ds, a1, bv.y);
  o0 = o0 > 0.f ? o0 : 0.f;
  o1 = o1 > 0.f ? o1 : 0.f;
  float2 w3v = *(const float2*)(W3 + 2 * lane);
  float p = o0 * w3v.x + o1 * w3v.y;
#pragma unroll
  for (int off = 32; off > 0; off >>= 1) p += __shfl_down(p, off, 64);
  if (lane == 0) z[node] = p;
}

// ---------------- scalar aggregate + bias + relu ----------------

__global__ void k_aggs(const float* __restrict__ z, const int* __restrict__ rowptr,
                       const EdgeRec* __restrict__ ep, const float* __restrict__ dis,
                       const float* __restrict__ b3, float* __restrict__ out, int N) {
  int n = blockIdx.x * blockDim.x + threadIdx.x;
  if (n >= N) return;
  float acc = 0.f;
  int end = rowptr[n + 1];
  for (int e = rowptr[n]; e < end; e++) {
    EdgeRec p = ep[e];
    acc = fmaf(__int_as_float(p.y), z[p.x], acc);
  }
  acc = fmaf(dis[n], acc, b3[0]);
  out[n] = acc > 0.f ? acc : 0.f;
}

// ---------------- launch ----------------

extern "C" void kernel_launch(void* const* d_in, const int* in_sizes, int n_in,
                              void* d_out, int out_size, void* d_ws, size_t ws_size,
                              hipStream_t stream) {
  const float* x  = (const float*)d_in[0];
  const int*   ei = (const int*)d_in[1];
  const float* ew = (const float*)d_in[2];
  const float* W1 = (const float*)d_in[3];
  const float* b1 = (const float*)d_in[4];
  const float* W2 = (const float*)d_in[5];
  const float* b2 = (const float*)d_in[6];
  const float* W3 = (const float*)d_in[7];
  const float* b3 = (const float*)d_in[8];
  int N = in_sizes[0] / NFEAT;
  int E = in_sizes[2];
  int M = E + N;
  const int* srcp = ei;
  const int* dstp = ei + E;

  char* p = (char*)d_ws;
  auto carve = [&](size_t bytes) -> void* {
    void* r = (void*)p;
    p += (bytes + 511) & ~(size_t)511;
    return r;
  };
  unsigned long long* packed = (unsigned long long*)carve(sizeof(unsigned long long) * N);
  int*     off    = (int*)  carve(sizeof(int) * E);
  int*     rowptr = (int*)  carve(sizeof(int) * (N + 1));
  float*   dis    = (float*)carve(sizeof(float) * N);
  int*     bsum   = (int*)  carve(sizeof(int) * 1024);
  EdgeRec* ep     = (EdgeRec*)carve(sizeof(EdgeRec) * M);
  float*   t1     = (float*)carve(sizeof(float) * (size_t)N * NFEAT);
  float*   t2     = (float*)carve(sizeof(float) * (size_t)N * NFEAT);
  float*   z      = (float*)carve(sizeof(float) * N);

  int gN = (N + 255) / 256, gE = (E + 255) / 256;
  int SB = (N + 1023) / 1024;

  k_init<<<gN, 256, 0, stream>>>(packed, N);
  k_count64<<<gE, 256, 0, stream>>>(dstp, ew, packed, off, E);
  k_dis<<<gN, 256, 0, stream>>>(packed, dis, N);
  k_scan1<<<SB, 256, 0, stream>>>(packed, bsum, N);
  k_scan2<<<1, 1024, 0, stream>>>(bsum, SB);
  k_scan3<<<SB, 256, 0, stream>>>(packed, bsum, rowptr, N, M);
  k_selfloop<<<gN, 256, 0, stream>>>(rowptr, dis, ep, N);
  k_fill<<<gE, 256, 0, stream>>>(srcp, dstp, ew, dis, rowptr, off, ep, E);

  int numTiles = (N + 63) / 64;   // 64 rows per block-tile (8 waves x 8 rows)
  int gg = 512;                   // 2 blocks/CU, persistent
  int gW = (N + 3) / 4;

  k_gemm128<<<gg, 512, 0, stream>>>(x, W1, t1, N, numTiles);
  k_agg128<<<gW, 256, 0, stream>>>(t1, rowptr, ep, dis, b1, t2, N);
  k_gemm128<<<gg, 512, 0, stream>>>(t2, W2, t1, N, numTiles);
  k_agg_final<<<gW, 256, 0, stream>>>(t1, rowptr, ep, dis, b2, W3, z, N);
  k_aggs<<<gN, 256, 0, stream>>>(z, rowptr, ep, dis, b3, (float*)d_out, N);
}